// Round 3
// baseline (717.677 us; speedup 1.0000x reference)
//
#include <hip/hip_runtime.h>
#include <stdint.h>

#define S_ 256
#define T_ 64
#define B_ 8
#define H_ 768
#define V_ 50257
#define R_ 512      // T*B
#define VP_ 50304   // V padded to multiple of 128

typedef __attribute__((ext_vector_type(8))) short short8;
typedef __attribute__((ext_vector_type(4))) float float4v;

__device__ __forceinline__ float bf2f(unsigned short u) {
  union { unsigned int i; float f; } x; x.i = ((unsigned int)u) << 16; return x.f;
}
__device__ __forceinline__ short f2bf(float f) {
  union { float f; unsigned int i; } x; x.f = f;
  unsigned int u = x.i;
  unsigned int r = u + 0x7fffu + ((u >> 16) & 1u);   // RNE
  return (short)(r >> 16);
}
__device__ __forceinline__ float tanh_fast(float x) {
  x = fminf(10.f, fmaxf(-10.f, x));
  float e = __expf(2.f * x);
  return (e - 1.f) * __builtin_amdgcn_rcpf(e + 1.f);
}

// ---- wave-level 64x64 GEMM over K=768, bf16 MFMA, direct-global (no LDS, no barriers) ----
// aBase: &A[mrow0 + (l&15)][(l>>4)*8], row stride 768 shorts
// bBase: &B[nrow0 + (l&15)][(l>>4)*8], row stride SB shorts
template<int SB>
__device__ __forceinline__ void wave_gemm768(const short* __restrict__ aBase,
                                             const short* __restrict__ bBase,
                                             float4v acc[4][4]) {
  short8 a0[4], b0[4];
#pragma unroll
  for (int mt = 0; mt < 4; ++mt) a0[mt] = *(const short8*)(aBase + (size_t)mt * 16 * 768);
#pragma unroll
  for (int nt = 0; nt < 4; ++nt) b0[nt] = *(const short8*)(bBase + (size_t)nt * 16 * SB);
#pragma unroll 2
  for (int kk = 32; kk < 768; kk += 32) {
    short8 a1[4], b1[4];
#pragma unroll
    for (int mt = 0; mt < 4; ++mt) a1[mt] = *(const short8*)(aBase + (size_t)mt * 16 * 768 + kk);
#pragma unroll
    for (int nt = 0; nt < 4; ++nt) b1[nt] = *(const short8*)(bBase + (size_t)nt * 16 * SB + kk);
#pragma unroll
    for (int mt = 0; mt < 4; ++mt)
#pragma unroll
      for (int nt = 0; nt < 4; ++nt)
        acc[mt][nt] = __builtin_amdgcn_mfma_f32_16x16x32_bf16(a0[mt], b0[nt], acc[mt][nt], 0, 0, 0);
#pragma unroll
    for (int i = 0; i < 4; ++i) { a0[i] = a1[i]; b0[i] = b1[i]; }
  }
#pragma unroll
  for (int mt = 0; mt < 4; ++mt)
#pragma unroll
    for (int nt = 0; nt < 4; ++nt)
      acc[mt][nt] = __builtin_amdgcn_mfma_f32_16x16x32_bf16(a0[mt], b0[nt], acc[mt][nt], 0, 0, 0);
}

// ---------------- 1. fp32 -> bf16 conversions + zero rowsums ----------------
__global__ __launch_bounds__(256) void cvt_kernel(const float* dec, const float* enc,
                                                  short* dec16, short* enc16, float* rowsums) {
  int i = blockIdx.x * 256 + threadIdx.x;
  if (i < R_) rowsums[i] = 0.f;
  const int nd = R_ * H_;            // 393216
  if (i < nd) dec16[i] = f2bf(dec[i]);
  else        enc16[i - nd] = f2bf(enc[i - nd]);   // grid sized exactly nd+ne
}

// ---------------- 2. W_attn [1536][768] -> WAT16 [768][1536] (transpose+cvt) ----------------
__global__ __launch_bounds__(256) void twat_kernel(const float* in, short* out) {
  __shared__ float tile[64][65];
  int n0 = blockIdx.x * 64;   // over 768 (out rows)
  int k0 = blockIdx.y * 64;   // over 1536
  int t = threadIdx.x;
  int c = t & 63, rsub = t >> 6;
#pragma unroll
  for (int i = 0; i < 16; ++i) {
    int r = i * 4 + rsub;
    tile[r][c] = in[(size_t)(k0 + r) * 768 + n0 + c];
  }
  __syncthreads();
#pragma unroll
  for (int i = 0; i < 16; ++i) {
    int nn = i * 4 + rsub;
    out[(size_t)(n0 + nn) * 1536 + k0 + c] = f2bf(tile[c][nn]);
  }
}

// ---------------- 2b. W_gen [768][V] fp32 -> WT16 [VP][768] bf16 (transpose+cvt) ------------
__global__ __launch_bounds__(256) void cvt_wt_kernel(const float* __restrict__ in,
                                                     short* __restrict__ out) {
  __shared__ float tile[64][65];
  int v0 = blockIdx.x * 64;
  int k0 = blockIdx.y * 64;
  int t = threadIdx.x;
  int c = t & 63, rsub = t >> 6;
#pragma unroll
  for (int i = 0; i < 16; ++i) {
    int r = i * 4 + rsub;                 // k within tile
    int v = v0 + c;
    tile[r][c] = (v < V_) ? in[(size_t)(k0 + r) * V_ + v] : 0.f;
  }
  __syncthreads();
  int cp = t & 31, nsub = t >> 5;         // 8 n-rows per pass
#pragma unroll
  for (int i = 0; i < 8; ++i) {
    int nn = i * 8 + nsub;
    unsigned int pk = (unsigned int)(unsigned short)f2bf(tile[2 * cp][nn]) |
                      ((unsigned int)(unsigned short)f2bf(tile[2 * cp + 1][nn]) << 16);
    *(unsigned int*)&out[(size_t)(v0 + nn) * 768 + k0 + 2 * cp] = pk;
  }
}

// ---------------- 3/4. proj GEMM: C[M][768] = A(bf16)[M][768] @ W + bias ----------------
// no-LDS wave GEMM; block = 4 waves stacked in m (256 m x 64 n). grid (M/256, 12).
__global__ __launch_bounds__(256) void gemm_proj(const short* __restrict__ A,
                                                 const short* __restrict__ BT,
                                                 int koff, const float* bias, float* C) {
  int t = threadIdx.x, w = t >> 6, l = t & 63;
  int ln = l & 15, kq = l >> 4;
  int m0 = blockIdx.x * 256 + w * 64;
  int n0 = blockIdx.y * 64;
  const short* aBase = A + (size_t)(m0 + ln) * 768 + kq * 8;
  const short* bBase = BT + (size_t)(n0 + ln) * 1536 + koff + kq * 8;
  float4v acc[4][4];
#pragma unroll
  for (int i = 0; i < 4; ++i)
#pragma unroll
    for (int j = 0; j < 4; ++j) acc[i][j] = float4v{0.f, 0.f, 0.f, 0.f};
  wave_gemm768<1536>(aBase, bBase, acc);
  int q4 = kq * 4;
#pragma unroll
  for (int nt = 0; nt < 4; ++nt) {
    int c = n0 + nt * 16 + ln;
    float bv = bias ? bias[c] : 0.f;
#pragma unroll
    for (int mt = 0; mt < 4; ++mt)
#pragma unroll
      for (int r = 0; r < 4; ++r) {
        int row = m0 + mt * 16 + q4 + r;
        C[(size_t)row * 768 + c] = acc[mt][nt][r] + bv;
      }
  }
}

// ---------------- 5. energy ----------------
__global__ __launch_bounds__(256) void energy_kernel(const float* __restrict__ dproj,
                                                     const float* __restrict__ eproj,
                                                     const float* vattn, const float* bv,
                                                     float* scores) {
  __shared__ float dch[16][65];
  __shared__ float ech[16][65];
  __shared__ float vch[64];
  int s0 = blockIdx.x * 16;
  int b  = blockIdx.y;
  int t0 = blockIdx.z * 16;
  int t = threadIdx.x;
  int sl = t & 15, tl = t >> 4;
  float acc = 0.f;
  for (int hc = 0; hc < 768; hc += 64) {
#pragma unroll
    for (int i = 0; i < 4; ++i) {
      int idx = i * 256 + t;
      int rr = idx >> 6, cc = idx & 63;
      dch[rr][cc] = dproj[(size_t)((t0 + rr) * 8 + b) * 768 + hc + cc];
      ech[rr][cc] = eproj[(size_t)((s0 + rr) * 8 + b) * 768 + hc + cc];
    }
    if (t < 64) vch[t] = vattn[hc + t];
    __syncthreads();
#pragma unroll 8
    for (int hh = 0; hh < 64; ++hh) {
      float x = dch[tl][hh] + ech[sl][hh];
      acc = fmaf(tanh_fast(x), vch[hh], acc);
    }
    __syncthreads();
  }
  scores[(size_t)((t0 + tl) * 8 + b) * 256 + s0 + sl] = acc + bv[0];
}

// ---------------- 6. masked softmax over s per row r ----------------
__global__ __launch_bounds__(256) void softmax_kernel(const float* scores, const int* sid, float* P) {
  __shared__ float red[256];
  int r = blockIdx.x, t = threadIdx.x, b = r & 7;
  float v = scores[(size_t)r * 256 + t];
  if (sid[t * 8 + b] == 0) v = -1e10f;
  red[t] = v;
  __syncthreads();
  for (int s = 128; s > 0; s >>= 1) {
    if (t < s) red[t] = fmaxf(red[t], red[t + s]);
    __syncthreads();
  }
  float m = red[0];
  __syncthreads();
  float e = __expf(v - m);
  red[t] = e;
  __syncthreads();
  for (int s = 128; s > 0; s >>= 1) {
    if (t < s) red[t] += red[t + s];
    __syncthreads();
  }
  P[(size_t)r * 256 + t] = e * (1.f / red[0]);
}

// ---------------- 7. ctx ----------------
__global__ __launch_bounds__(256) void ctx_kernel(const float* __restrict__ P,
                                                  const float* __restrict__ enc, float* ctx) {
  __shared__ float Pl[16][256];
  int h0 = blockIdx.x * 64;
  int b  = blockIdx.y;
  int tg = blockIdx.z;
  int t = threadIdx.x;
  int hl = t & 63, wv = t >> 6;
#pragma unroll
  for (int i = 0; i < 16; ++i) {
    int idx = i * 256 + t;
    int tt = idx >> 8, s = idx & 255;
    Pl[tt][s] = P[(size_t)((tg * 16 + tt) * 8 + b) * 256 + s];
  }
  __syncthreads();
  float acc[4] = {0.f, 0.f, 0.f, 0.f};
#pragma unroll 4
  for (int s = 0; s < 256; ++s) {
    float e = enc[(size_t)(s * 8 + b) * 768 + h0 + hl];
#pragma unroll
    for (int j = 0; j < 4; ++j)
      acc[j] = fmaf(Pl[wv * 4 + j][s], e, acc[j]);
  }
#pragma unroll
  for (int j = 0; j < 4; ++j)
    ctx[(size_t)((tg * 16 + wv * 4 + j) * 8 + b) * 768 + h0 + hl] = acc[j];
}

// ---------------- 8. p_gen ----------------
__global__ __launch_bounds__(256) void pgen_kernel(const float* dec, const float* ctx,
                                                   const float* tgt, const float* Wp,
                                                   const float* bp, float* pgen) {
  __shared__ float red[256];
  int r = blockIdx.x, t = threadIdx.x;
  float s = 0.f;
  for (int h = t; h < 768; h += 256) {
    s = fmaf(dec[(size_t)r * 768 + h], Wp[h], s);
    s = fmaf(ctx[(size_t)r * 768 + h], Wp[768 + h], s);
    s = fmaf(tgt[(size_t)r * 768 + h], Wp[1536 + h], s);
  }
  red[t] = s;
  __syncthreads();
  for (int st = 128; st > 0; st >>= 1) {
    if (t < st) red[t] += red[t + st];
    __syncthreads();
  }
  if (t == 0) pgen[r] = 1.f / (1.f + __expf(-(red[0] + bp[0])));
}

// ---------------- 9. vocab GEMM: E = exp(A @ WT^T + b_gen), no-LDS direct-global ---------
// block = 4 waves stacked in m (256 m x 64 n). grid (2, 786), x fastest so the two
// m-halves of each n-stripe are dispatched together (B-stripe L1/L2/L3 temporal reuse).
__global__ __launch_bounds__(256) void gemm_vocab(const short* __restrict__ A,
                                                  const short* __restrict__ BT,
                                                  const float* __restrict__ bgen,
                                                  short* __restrict__ E, float* rowsums) {
  int t = threadIdx.x, w = t >> 6, l = t & 63;
  int ln = l & 15, kq = l >> 4;
  int m0 = blockIdx.x * 256 + w * 64;
  int n0 = blockIdx.y * 64;
  const short* aBase = A + (size_t)(m0 + ln) * 768 + kq * 8;
  const short* bBase = BT + (size_t)(n0 + ln) * 768 + kq * 8;
  float4v acc[4][4];
#pragma unroll
  for (int i = 0; i < 4; ++i)
#pragma unroll
    for (int j = 0; j < 4; ++j) acc[i][j] = float4v{0.f, 0.f, 0.f, 0.f};
  wave_gemm768<768>(aBase, bBase, acc);

  // epilogue: exp, store bf16 (zeros in pad cols), per-row partial sums
  int q4 = kq * 4;
  float rs[4][4];
#pragma unroll
  for (int i = 0; i < 4; ++i)
#pragma unroll
    for (int j = 0; j < 4; ++j) rs[i][j] = 0.f;
#pragma unroll
  for (int nt = 0; nt < 4; ++nt) {
    int c = n0 + nt * 16 + ln;
    bool valid = c < V_;
    float bg = valid ? bgen[c] : 0.f;
#pragma unroll
    for (int mt = 0; mt < 4; ++mt)
#pragma unroll
      for (int r = 0; r < 4; ++r) {
        float e = valid ? __expf(acc[mt][nt][r] + bg) : 0.f;
        int row = m0 + mt * 16 + q4 + r;
        E[(size_t)row * VP_ + c] = f2bf(e);
        rs[mt][r] += e;
      }
  }
#pragma unroll
  for (int mt = 0; mt < 4; ++mt)
#pragma unroll
    for (int r = 0; r < 4; ++r) {
      float v = rs[mt][r];
      v += __shfl_xor(v, 1);
      v += __shfl_xor(v, 2);
      v += __shfl_xor(v, 4);
      v += __shfl_xor(v, 8);
      if (ln == 0) atomicAdd(&rowsums[m0 + mt * 16 + q4 + r], v);
    }
}

// ---------------- 10. final: out = E*pg/Z then scatter-add (chunk-local) ----------------
__global__ __launch_bounds__(256) void final_kernel(const short* __restrict__ E,
                                                    const float* __restrict__ P,
                                                    const float* pgen, const float* rowsums,
                                                    const int* sid, float* __restrict__ out) {
  int r = blockIdx.y, t = threadIdx.x, b = r & 7;
  int lo = blockIdx.x * 2048, hi = lo + 2048;
  float pg = pgen[r];
  float scale = pg / rowsums[r];
  const short* Er = E + (size_t)r * VP_;
  float* outr = out + (size_t)r * V_;
  int c0 = lo + t * 8;
  if (c0 < V_) {
    short8 ev = *(const short8*)&Er[c0];
#pragma unroll
    for (int j = 0; j < 8; ++j) {
      int c = c0 + j;
      if (c < V_) outr[c] = bf2f((unsigned short)ev[j]) * scale;
    }
  }
  __syncthreads();
  int idx = sid[t * 8 + b];
  if (idx >= lo && idx < hi) {
    float ap = (1.f - pg) * P[(size_t)r * 256 + t];
    atomicAdd(&outr[idx], ap);
  }
}

extern "C" void kernel_launch(void* const* d_in, const int* in_sizes, int n_in,
                              void* d_out, int out_size, void* d_ws, size_t ws_size,
                              hipStream_t stream) {
  const float* enc  = (const float*)d_in[0];
  const float* dec  = (const float*)d_in[1];
  const int*   sid  = (const int*)d_in[2];
  const float* tgt  = (const float*)d_in[3];
  const float* Wat  = (const float*)d_in[4];
  const float* batt = (const float*)d_in[5];
  const float* vatt = (const float*)d_in[6];
  const float* bv   = (const float*)d_in[7];
  const float* Wp   = (const float*)d_in[8];
  const float* bp   = (const float*)d_in[9];
  const float* Wg   = (const float*)d_in[10];
  const float* bg   = (const float*)d_in[11];
  float* out = (float*)d_out;

  char* ws = (char*)d_ws;
  size_t off = 0;
  auto alloc = [&](size_t bytes) -> char* {
    char* p = ws + off;
    off += (bytes + 255) & ~(size_t)255;
    return p;
  };
  short* E16     = (short*)alloc((size_t)R_ * VP_ * 2);     // 51.5 MB
  short* WT16    = (short*)alloc((size_t)VP_ * H_ * 2);     // 77.3 MB
  short* dec16   = (short*)alloc((size_t)R_ * H_ * 2);
  short* enc16   = (short*)alloc((size_t)S_ * B_ * H_ * 2);
  short* WAT16   = (short*)alloc((size_t)H_ * 1536 * 2);
  float* dproj   = (float*)alloc((size_t)R_ * H_ * 4);
  float* eproj   = (float*)alloc((size_t)S_ * B_ * H_ * 4);
  float* scores  = (float*)alloc((size_t)R_ * 256 * 4);
  float* P       = (float*)alloc((size_t)R_ * 256 * 4);
  float* ctx     = (float*)alloc((size_t)R_ * H_ * 4);
  float* pgen    = (float*)alloc(R_ * 4);
  float* rowsums = (float*)alloc(R_ * 4);

  cvt_kernel<<<7680, 256, 0, stream>>>(dec, enc, dec16, enc16, rowsums);
  twat_kernel<<<dim3(12, 24), 256, 0, stream>>>(Wat, WAT16);
  cvt_wt_kernel<<<dim3(786, 12), 256, 0, stream>>>(Wg, WT16);
  gemm_proj<<<dim3(2, 12), 256, 0, stream>>>(dec16, WAT16, 0, nullptr, dproj);
  gemm_proj<<<dim3(8, 12), 256, 0, stream>>>(enc16, WAT16, 768, batt, eproj);
  energy_kernel<<<dim3(16, 8, 4), 256, 0, stream>>>(dproj, eproj, vatt, bv, scores);
  softmax_kernel<<<512, 256, 0, stream>>>(scores, sid, P);
  ctx_kernel<<<dim3(12, 8, 4), 256, 0, stream>>>(P, enc, ctx);
  pgen_kernel<<<512, 256, 0, stream>>>(dec, ctx, tgt, Wp, bp, pgen);
  gemm_vocab<<<dim3(2, 786), 256, 0, stream>>>(dec16, WT16, bg, E16, rowsums);
  final_kernel<<<dim3(25, 512), 256, 0, stream>>>(E16, P, pgen, rowsums, sid, out);
}